// Round 13
// baseline (218.818 us; speedup 1.0000x reference)
//
#include <hip/hip_runtime.h>
#include <hip/hip_bf16.h>

// Fused MHA forward (B=8, I=J=1024, WIDTH=512, NH=8, HD=64), fp32 in/out.
// R13 = R12 + MEASUREMENT ROUND: attn_kernel launched TWICE (idempotent) so
// this round's dur_us delta vs R12 (140.4us) equals attn_kernel's duration.
// No other changes. Next round reverts to single launch and targets whichever
// side of the split holds the slack.

typedef __hip_bfloat16 bf16;
typedef __attribute__((ext_vector_type(8))) short bf16x8;   // MFMA A/B frag (4 VGPR)
typedef __attribute__((ext_vector_type(4))) float f32x4;    // MFMA C/D frag, nt-store vec

#define BATCH 8
#define SEQ   1024
#define WIDTH 512
#define NHEAD 8
#define HD    64
#define SCALE_F 0.044194173824159216f     // 512^-0.5 (width, per reference!)

static __device__ __forceinline__ unsigned short f2bf(float x) {
  union { float f; unsigned u; } a; a.f = x;
  unsigned r = a.u + 0x7fffu + ((a.u >> 16) & 1u);   // RNE
  return (unsigned short)(r >> 16);
}
static __device__ __forceinline__ float bf2f(unsigned short u) {
  union { unsigned u; float f; } a; a.u = ((unsigned)u) << 16; return a.f;
}

static __device__ __forceinline__ void gload_lds16(const void* g, void* l) {
  __builtin_amdgcn_global_load_lds((const __attribute__((address_space(1))) void*)g,
                                   (__attribute__((address_space(3))) void*)l,
                                   16, 0, 0);
}

// Swizzled LDS tile: rows of 64 bf16 (128B); 16B-unit phys col = logical ^ (row&7).
static __device__ __forceinline__ bf16x8 frag_ld(const short* tile, int row, int c16) {
  int p = c16 ^ (row & 7);
  return *(const bf16x8*)(tile + row*64 + p*8);
}

// ---------------- cast fp32 -> bf16 (q,k,v + 4 weights) ----------------
__global__ void cast_all_kernel(const float* __restrict__ q, const float* __restrict__ k,
                                const float* __restrict__ v, const float* __restrict__ wq,
                                const float* __restrict__ wk, const float* __restrict__ wv,
                                const float* __restrict__ wo, bf16* __restrict__ wsb) {
  const long NQ = 1048576;   // float4 groups per q/k/v (8192*512/4)
  const long NW = 65536;     // per weight (512*512/4)
  long g = (long)blockIdx.x * blockDim.x + threadIdx.x;
  const float* src; bf16* dst; long o;
  if (g < 3*NQ) {
    int t = (int)(g / NQ); o = g - (long)t*NQ;
    src = (t==0) ? q : ((t==1) ? k : v);
    dst = wsb + (size_t)t * 4194304;
  } else {
    long g2 = g - 3*NQ;
    if (g2 >= 4*NW) return;
    int t = (int)(g2 / NW); o = g2 - (long)t*NW;
    src = (t==0) ? wq : ((t==1) ? wk : ((t==2) ? wv : wo));
    dst = wsb + (size_t)3*4194304 + (size_t)t * 262144;
  }
  float4 f = ((const float4*)src)[o];
  ushort4 r4;
  r4.x = f2bf(f.x); r4.y = f2bf(f.y); r4.z = f2bf(f.z); r4.w = f2bf(f.w);
  ((ushort4*)dst)[o] = r4;
}

// ---------------- QKV GEMM: C[8192][512] = A @ W^T (merged q,k,v) ----------------
__global__ __launch_bounds__(256) void gemm_qkv(const bf16* __restrict__ A0, const bf16* __restrict__ A1,
                                                const bf16* __restrict__ A2, const bf16* __restrict__ W0,
                                                const bf16* __restrict__ W1, const bf16* __restrict__ W2,
                                                bf16* __restrict__ C0, bf16* __restrict__ C1,
                                                bf16* __restrict__ C2) {
  __shared__ short As[2][128*64];
  __shared__ short Bs[2][128*64];

  const int bid = blockIdx.x;               // 768 blocks
  const int xcd = bid & 7;
  const int idx = bid >> 3;                 // 0..95
  const int g   = xcd*24 + (idx >> 2);      // 0..191
  const int y   = idx & 3;
  const int z   = g >> 6;                   // 0:q 1:k 2:v
  const int m   = g & 63;

  const bf16* A  = (z==0) ? A0 : ((z==1) ? A1 : A2);
  const bf16* Bw = (z==0) ? W0 : ((z==1) ? W1 : W2);
  bf16* Cout     = (z==0) ? C0 : ((z==1) ? C1 : C2);

  const int lane = threadIdx.x & 63;
  const int wid  = threadIdx.x >> 6;
  const int m0 = m * 128;
  const int n0 = y * 128;
  const int wm = (wid >> 1) * 64;
  const int wn = (wid & 1) * 64;
  const int lrow = lane >> 3;
  const int swz  = ((lane & 7) ^ lrow) * 8;

  const f32x4 zero4 = {0.f,0.f,0.f,0.f};
  f32x4 acc[4][4];
  for (int i=0;i<4;++i) for (int j=0;j<4;++j) acc[i][j] = zero4;

  auto stage = [&](int buf, int t) {
    const int k0 = t * 64;
    for (int i = 0; i < 4; ++i) {
      int c = wid*4 + i;
      int row = c*8 + lrow;
      gload_lds16(A  + (size_t)(m0 + row)*WIDTH + k0 + swz, &As[buf][c*512]);
      gload_lds16(Bw + (size_t)(n0 + row)*WIDTH + k0 + swz, &Bs[buf][c*512]);
    }
  };

  stage(0, 0);
  asm volatile("s_waitcnt vmcnt(0)" ::: "memory");
  __syncthreads();
  int cur = 0;

  for (int t = 0; t < 8; ++t) {
    if (t < 7) stage(cur ^ 1, t + 1);
    for (int kc = 0; kc < 2; ++kc) {
      bf16x8 af[4], bfr[4];
      for (int mf=0; mf<4; ++mf) af[mf]  = frag_ld(&As[cur][0], wm + mf*16 + (lane&15), (lane>>4) + kc*4);
      for (int nf=0; nf<4; ++nf) bfr[nf] = frag_ld(&Bs[cur][0], wn + nf*16 + (lane&15), (lane>>4) + kc*4);
      for (int mf=0; mf<4; ++mf)
        for (int nf=0; nf<4; ++nf)
          acc[mf][nf] = __builtin_amdgcn_mfma_f32_16x16x32_bf16(af[mf], bfr[nf], acc[mf][nf], 0,0,0);
    }
    if (t < 7) {
      asm volatile("s_waitcnt vmcnt(0)" ::: "memory");
      __syncthreads();
      cur ^= 1;
    }
  }
  for (int mf=0; mf<4; ++mf)
    for (int nf=0; nf<4; ++nf) {
      int col = n0 + wn + nf*16 + (lane & 15);
      for (int r=0; r<4; ++r) {
        int row = m0 + wm + mf*16 + (lane>>4)*4 + r;
        ((unsigned short*)Cout)[(size_t)row*WIDTH + col] = f2bf(acc[mf][nf][r]);
      }
    }
}

// ---------------- output GEMM: x[8192][512] = ctx @ Wo^T, fp32 nt out ----------------
__global__ __launch_bounds__(256) void gemm_out(const bf16* __restrict__ A,
                                                const bf16* __restrict__ Bw,
                                                float* __restrict__ Cout) {
  __shared__ short As[2][128*64];
  __shared__ short Bs[2][64*64];

  const int bid = blockIdx.x;                // 512 blocks
  const int xcd = bid & 7;
  const int idx = bid >> 3;                  // 0..63
  const int m   = xcd*8 + (idx >> 3);        // 0..63
  const int y   = idx & 7;                   // 0..7 (64-col panels)

  const int lane = threadIdx.x & 63;
  const int wid  = threadIdx.x >> 6;
  const int m0 = m * 128;
  const int n0 = y * 64;
  const int wm = (wid >> 1) * 64;
  const int wn = (wid & 1) * 32;
  const int lrow = lane >> 3;
  const int swz  = ((lane & 7) ^ lrow) * 8;

  const f32x4 zero4 = {0.f,0.f,0.f,0.f};
  f32x4 acc[4][2];
  for (int i=0;i<4;++i) for (int j=0;j<2;++j) acc[i][j] = zero4;

  auto stage = [&](int buf, int t) {
    const int k0 = t * 64;
    for (int i = 0; i < 4; ++i) {
      int c = wid*4 + i;
      int row = c*8 + lrow;
      gload_lds16(A + (size_t)(m0 + row)*WIDTH + k0 + swz, &As[buf][c*512]);
    }
    for (int i = 0; i < 2; ++i) {
      int c = wid*2 + i;
      int row = c*8 + lrow;
      gload_lds16(Bw + (size_t)(n0 + row)*WIDTH + k0 + swz, &Bs[buf][c*512]);
    }
  };

  stage(0, 0);
  asm volatile("s_waitcnt vmcnt(0)" ::: "memory");
  __syncthreads();
  int cur = 0;

  for (int t = 0; t < 8; ++t) {
    if (t < 7) stage(cur ^ 1, t + 1);
    for (int kc = 0; kc < 2; ++kc) {
      bf16x8 af[4], bfr[2];
      for (int mf=0; mf<4; ++mf) af[mf]  = frag_ld(&As[cur][0], wm + mf*16 + (lane&15), (lane>>4) + kc*4);
      for (int nf=0; nf<2; ++nf) bfr[nf] = frag_ld(&Bs[cur][0], wn + nf*16 + (lane&15), (lane>>4) + kc*4);
      for (int mf=0; mf<4; ++mf)
        for (int nf=0; nf<2; ++nf)
          acc[mf][nf] = __builtin_amdgcn_mfma_f32_16x16x32_bf16(af[mf], bfr[nf], acc[mf][nf], 0,0,0);
    }
    if (t < 7) {
      asm volatile("s_waitcnt vmcnt(0)" ::: "memory");
      __syncthreads();
      cur ^= 1;
    }
  }
  for (int mf=0; mf<4; ++mf)
    for (int nf=0; nf<2; ++nf) {
      int col = n0 + wn + nf*16 + (lane & 15);
      for (int r=0; r<4; ++r) {
        int row = m0 + wm + mf*16 + (lane>>4)*4 + r;
        __builtin_nontemporal_store(acc[mf][nf][r], Cout + (size_t)row*WIDTH + col);
      }
    }
}

// ---------------- V transpose: per head (1024,64) -> (64,1024) ----------------
__global__ __launch_bounds__(256) void transpose_v(const bf16* __restrict__ Vh,
                                                   bf16* __restrict__ Vt) {
  __shared__ short t[64][72];
  int h  = blockIdx.x >> 4;
  int j0 = (blockIdx.x & 15) * 64;
  const bf16* src = Vh + (size_t)h * (SEQ*HD);
  bf16* dst = Vt + (size_t)h * (SEQ*HD);
  int tid = threadIdx.x;
  int r  = tid >> 2;
  int c0 = (tid & 3) * 16;
  bf16x8 v0 = *(const bf16x8*)(src + (size_t)(j0 + r)*HD + c0);
  bf16x8 v1 = *(const bf16x8*)(src + (size_t)(j0 + r)*HD + c0 + 8);
  for (int i = 0; i < 8; ++i) { t[r][c0+i] = v0[i]; t[r][c0+8+i] = v1[i]; }
  __syncthreads();
  bf16x8 w0, w1;
  for (int i = 0; i < 8; ++i) { w0[i] = t[c0+i][r]; w1[i] = t[c0+8+i][r]; }
  *(bf16x8*)(dst + (size_t)r*SEQ + j0 + c0)     = w0;
  *(bf16x8*)(dst + (size_t)r*SEQ + j0 + c0 + 8) = w1;
}

// ---------------- fused attention (2-pass, 8-wave blocks) ----------------
__global__ __launch_bounds__(512) void attn_kernel(const bf16* __restrict__ Qh,
                                                   const bf16* __restrict__ Kh,
                                                   const bf16* __restrict__ Vt,
                                                   float* __restrict__ attn_out,
                                                   bf16* __restrict__ ctx) {
  __shared__ short Ks[2][64*64];
  __shared__ short Vs[2][64*64];
  __shared__ short Ws[8][16*64];

  const int lane = threadIdx.x & 63;
  const int wid  = threadIdx.x >> 6;         // 0..7
  const int bid  = blockIdx.x;
  const int xcd  = bid & 7;
  const int idx  = bid >> 3;                 // 0..63
  const int h    = xcd*8 + (idx >> 3);       // 8 heads/XCD
  const int i0   = (idx & 7) * 128;          // 8 i-blocks of 128 rows per head
  const int b  = h >> 3;
  const int nh = h & 7;

  const bf16* Qhead  = Qh + (size_t)h * (SEQ*HD);
  const bf16* Khead  = Kh + (size_t)h * (SEQ*HD);
  const bf16* Vthead = Vt + (size_t)h * (SEQ*HD);

  const int lrow = lane >> 3;
  const int swz  = ((lane & 7) ^ lrow) * 8;

  const int qrow = i0 + wid*16 + (lane & 15);
  bf16x8 qf[2];
  qf[0] = *(const bf16x8*)(Qhead + (size_t)qrow*HD + (lane>>4)*8);
  qf[1] = *(const bf16x8*)(Qhead + (size_t)qrow*HD + 32 + (lane>>4)*8);

  const f32x4 zero4 = {0.f,0.f,0.f,0.f};

  auto stageK = [&](int buf, int jt) {       // 1 chunk per wave
    const int j0 = jt * 64;
    gload_lds16(Khead + (size_t)(j0 + wid*8 + lrow)*HD + swz, &Ks[buf][wid*512]);
  };
  auto stageV = [&](int buf, int jt) {
    const int j0 = jt * 64;
    gload_lds16(Vthead + (size_t)(wid*8 + lrow)*SEQ + j0 + swz, &Vs[buf][wid*512]);
  };

  // ---- pass A: denominators ----
  float lsum[4] = {0.f,0.f,0.f,0.f};
  stageK(0, 0);
  asm volatile("s_waitcnt vmcnt(0)" ::: "memory");
  __syncthreads();
  int cur = 0;
  for (int jt = 0; jt < 16; ++jt) {
    if (jt < 15) stageK(cur ^ 1, jt + 1);
    f32x4 sac[4] = {zero4, zero4, zero4, zero4};
    __builtin_amdgcn_s_setprio(1);
    for (int kc = 0; kc < 2; ++kc)
      for (int jf = 0; jf < 4; ++jf) {
        bf16x8 kf = frag_ld(&Ks[cur][0], jf*16 + (lane & 15), (lane>>4) + kc*4);
        sac[jf] = __builtin_amdgcn_mfma_f32_16x16x32_bf16(qf[kc], kf, sac[jf], 0, 0, 0);
      }
    __builtin_amdgcn_s_setprio(0);
    for (int jf = 0; jf < 4; ++jf)
      for (int r = 0; r < 4; ++r)
        lsum[r] += __expf(sac[jf][r] * SCALE_F);
    if (jt < 15) {
      asm volatile("s_waitcnt vmcnt(0)" ::: "memory");
      __syncthreads();
      cur ^= 1;
    }
  }
  for (int m = 1; m < 16; m <<= 1)
    for (int r = 0; r < 4; ++r)
      lsum[r] += __shfl_xor(lsum[r], m, 64);
  float linv[4];
  for (int r = 0; r < 4; ++r) linv[r] = 1.0f / lsum[r];
  __syncthreads();

  // ---- pass B ----
  f32x4 cacc[4] = {zero4, zero4, zero4, zero4};
  short* Wsw = &Ws[wid][0];
  float* awbase = attn_out + (size_t)((size_t)h*SEQ + i0 + wid*16)*SEQ;
  stageK(0, 0); stageV(0, 0);
  asm volatile("s_waitcnt vmcnt(0)" ::: "memory");
  __syncthreads();
  cur = 0;
  for (int jt = 0; jt < 16; ++jt) {
    if (jt < 15) { stageK(cur ^ 1, jt + 1); stageV(cur ^ 1, jt + 1); }  // 2 loads (oldest)
    const int j0 = jt * 64;
    f32x4 sac[4] = {zero4, zero4, zero4, zero4};
    __builtin_amdgcn_s_setprio(1);
    for (int kc = 0; kc < 2; ++kc)
      for (int jf = 0; jf < 4; ++jf) {
        bf16x8 kf = frag_ld(&Ks[cur][0], jf*16 + (lane & 15), (lane>>4) + kc*4);
        sac[jf] = __builtin_amdgcn_mfma_f32_16x16x32_bf16(qf[kc], kf, sac[jf], 0, 0, 0);
      }
    __builtin_amdgcn_s_setprio(0);
    for (int jf = 0; jf < 4; ++jf)
      for (int r = 0; r < 4; ++r) {
        float w = __expf(sac[jf][r] * SCALE_F) * linv[r];
        int row = (lane>>4)*4 + r;
        int col = jf*16 + (lane & 15);
        Wsw[row*64 + (((col>>3) ^ (row & 7))<<3) + (col & 7)] = (short)f2bf(w);
      }
    asm volatile("s_waitcnt lgkmcnt(0)" ::: "memory");
    __builtin_amdgcn_s_setprio(1);
    for (int kc = 0; kc < 2; ++kc) {
      bf16x8 wa = frag_ld(Wsw, lane & 15, (lane>>4) + kc*4);
      for (int df = 0; df < 4; ++df) {
        bf16x8 vb = frag_ld(&Vs[cur][0], df*16 + (lane & 15), (lane>>4) + kc*4);
        cacc[df] = __builtin_amdgcn_mfma_f32_16x16x32_bf16(wa, vb, cacc[df], 0, 0, 0);
      }
    }
    __builtin_amdgcn_s_setprio(0);
    #pragma unroll
    for (int s = 0; s < 4; ++s) {
      int row = (lane>>4) + s*4;
      int lu  = (lane & 15) >> 1;
      uint2 pv = *(const uint2*)(Wsw + row*64 + ((lu ^ (row & 7)) << 3) + (lane & 1)*4);
      f32x4 o;
      o[0] = bf2f((unsigned short)(pv.x & 0xffff));
      o[1] = bf2f((unsigned short)(pv.x >> 16));
      o[2] = bf2f((unsigned short)(pv.y & 0xffff));
      o[3] = bf2f((unsigned short)(pv.y >> 16));
      __builtin_nontemporal_store(o,
          (f32x4*)(awbase + (size_t)row*SEQ + j0 + (lane & 15)*4));
    }
    if (jt < 15) {
      asm volatile("s_waitcnt vmcnt(16) lgkmcnt(0)" ::: "memory");
      __builtin_amdgcn_s_barrier();
      cur ^= 1;
    }
  }
  for (int df = 0; df < 4; ++df)
    for (int r = 0; r < 4; ++r) {
      int irow = i0 + wid*16 + (lane>>4)*4 + r;
      ((unsigned short*)ctx)[(size_t)(b*SEQ + irow)*WIDTH + nh*HD + df*16 + (lane & 15)]
          = f2bf(cacc[df][r]);
    }
}

// ---------------- launcher ----------------
extern "C" void kernel_launch(void* const* d_in, const int* in_sizes, int n_in,
                              void* d_out, int out_size, void* d_ws, size_t ws_size,
                              hipStream_t stream) {
  const float* q  = (const float*)d_in[0];
  const float* k  = (const float*)d_in[1];
  const float* v  = (const float*)d_in[2];
  const float* wq = (const float*)d_in[3];
  const float* wk = (const float*)d_in[4];
  const float* wv = (const float*)d_in[5];
  const float* wo = (const float*)d_in[6];

  bf16* wsb = (bf16*)d_ws;
  bf16* qb  = wsb;
  bf16* kb  = qb + 4194304;
  bf16* vb  = kb + 4194304;
  bf16* wqb = vb + 4194304;
  bf16* wkb = wqb + 262144;
  bf16* wvb = wkb + 262144;
  bf16* wob = wvb + 262144;
  bf16* Qh  = wob + 262144;
  bf16* Kh  = Qh + 4194304;
  bf16* Vh  = Kh + 4194304;
  bf16* Vt  = Vh + 4194304;
  bf16* ctx = Vt + 4194304;

  float* x_out    = (float*)d_out;             // (8,1024,512)
  float* attn_out = (float*)d_out + 4194304;   // (8,8,1024,1024)

  cast_all_kernel<<<13312, 256, 0, stream>>>(q, k, v, wq, wk, wv, wo, wsb);
  gemm_qkv<<<768, 256, 0, stream>>>(qb, kb, vb, wqb, wkb, wvb, Qh, Kh, Vh);
  transpose_v<<<1024, 256, 0, stream>>>(Vh, Vt);
  attn_kernel<<<512, 512, 0, stream>>>(Qh, Kh, Vt, attn_out, ctx);
  attn_kernel<<<512, 512, 0, stream>>>(Qh, Kh, Vt, attn_out, ctx);  // MEASUREMENT duplicate
  gemm_out<<<512, 256, 0, stream>>>(ctx, wob, x_out);
}

// Round 14
// 129.304 us; speedup vs baseline: 1.6923x; 1.6923x over previous
//
#include <hip/hip_runtime.h>
#include <hip/hip_bf16.h>

// Fused MHA forward (B=8, I=J=1024, WIDTH=512, NH=8, HD=64), fp32 in/out.
// R14 = R12 + ONE change: attention KVBLK 64->128 (two 64-col sub-rounds per
// barrier; 8 barriers/pass instead of 16; exact vmcnt(8) at the barrier).
// Measured R13: attn = 78us of the 140.4 total. LDS 80KB, 2 blocks/CU.

typedef __hip_bfloat16 bf16;
typedef __attribute__((ext_vector_type(8))) short bf16x8;   // MFMA A/B frag (4 VGPR)
typedef __attribute__((ext_vector_type(4))) float f32x4;    // MFMA C/D frag, nt-store vec

#define BATCH 8
#define SEQ   1024
#define WIDTH 512
#define NHEAD 8
#define HD    64
#define SCALE_F 0.044194173824159216f     // 512^-0.5 (width, per reference!)

static __device__ __forceinline__ unsigned short f2bf(float x) {
  union { float f; unsigned u; } a; a.f = x;
  unsigned r = a.u + 0x7fffu + ((a.u >> 16) & 1u);   // RNE
  return (unsigned short)(r >> 16);
}
static __device__ __forceinline__ float bf2f(unsigned short u) {
  union { unsigned u; float f; } a; a.u = ((unsigned)u) << 16; return a.f;
}

static __device__ __forceinline__ void gload_lds16(const void* g, void* l) {
  __builtin_amdgcn_global_load_lds((const __attribute__((address_space(1))) void*)g,
                                   (__attribute__((address_space(3))) void*)l,
                                   16, 0, 0);
}

// Swizzled LDS tile: rows of 64 bf16 (128B); 16B-unit phys col = logical ^ (row&7).
static __device__ __forceinline__ bf16x8 frag_ld(const short* tile, int row, int c16) {
  int p = c16 ^ (row & 7);
  return *(const bf16x8*)(tile + row*64 + p*8);
}

// ---------------- cast fp32 -> bf16 (q,k,v + 4 weights) ----------------
__global__ void cast_all_kernel(const float* __restrict__ q, const float* __restrict__ k,
                                const float* __restrict__ v, const float* __restrict__ wq,
                                const float* __restrict__ wk, const float* __restrict__ wv,
                                const float* __restrict__ wo, bf16* __restrict__ wsb) {
  const long NQ = 1048576;   // float4 groups per q/k/v (8192*512/4)
  const long NW = 65536;     // per weight (512*512/4)
  long g = (long)blockIdx.x * blockDim.x + threadIdx.x;
  const float* src; bf16* dst; long o;
  if (g < 3*NQ) {
    int t = (int)(g / NQ); o = g - (long)t*NQ;
    src = (t==0) ? q : ((t==1) ? k : v);
    dst = wsb + (size_t)t * 4194304;
  } else {
    long g2 = g - 3*NQ;
    if (g2 >= 4*NW) return;
    int t = (int)(g2 / NW); o = g2 - (long)t*NW;
    src = (t==0) ? wq : ((t==1) ? wk : ((t==2) ? wv : wo));
    dst = wsb + (size_t)3*4194304 + (size_t)t * 262144;
  }
  float4 f = ((const float4*)src)[o];
  ushort4 r4;
  r4.x = f2bf(f.x); r4.y = f2bf(f.y); r4.z = f2bf(f.z); r4.w = f2bf(f.w);
  ((ushort4*)dst)[o] = r4;
}

// ---------------- QKV GEMM: C[8192][512] = A @ W^T (merged q,k,v) ----------------
__global__ __launch_bounds__(256) void gemm_qkv(const bf16* __restrict__ A0, const bf16* __restrict__ A1,
                                                const bf16* __restrict__ A2, const bf16* __restrict__ W0,
                                                const bf16* __restrict__ W1, const bf16* __restrict__ W2,
                                                bf16* __restrict__ C0, bf16* __restrict__ C1,
                                                bf16* __restrict__ C2) {
  __shared__ short As[2][128*64];
  __shared__ short Bs[2][128*64];

  const int bid = blockIdx.x;               // 768 blocks
  const int xcd = bid & 7;
  const int idx = bid >> 3;                 // 0..95
  const int g   = xcd*24 + (idx >> 2);      // 0..191
  const int y   = idx & 3;
  const int z   = g >> 6;                   // 0:q 1:k 2:v
  const int m   = g & 63;

  const bf16* A  = (z==0) ? A0 : ((z==1) ? A1 : A2);
  const bf16* Bw = (z==0) ? W0 : ((z==1) ? W1 : W2);
  bf16* Cout     = (z==0) ? C0 : ((z==1) ? C1 : C2);

  const int lane = threadIdx.x & 63;
  const int wid  = threadIdx.x >> 6;
  const int m0 = m * 128;
  const int n0 = y * 128;
  const int wm = (wid >> 1) * 64;
  const int wn = (wid & 1) * 64;
  const int lrow = lane >> 3;
  const int swz  = ((lane & 7) ^ lrow) * 8;

  const f32x4 zero4 = {0.f,0.f,0.f,0.f};
  f32x4 acc[4][4];
  for (int i=0;i<4;++i) for (int j=0;j<4;++j) acc[i][j] = zero4;

  auto stage = [&](int buf, int t) {
    const int k0 = t * 64;
    for (int i = 0; i < 4; ++i) {
      int c = wid*4 + i;
      int row = c*8 + lrow;
      gload_lds16(A  + (size_t)(m0 + row)*WIDTH + k0 + swz, &As[buf][c*512]);
      gload_lds16(Bw + (size_t)(n0 + row)*WIDTH + k0 + swz, &Bs[buf][c*512]);
    }
  };

  stage(0, 0);
  asm volatile("s_waitcnt vmcnt(0)" ::: "memory");
  __syncthreads();
  int cur = 0;

  for (int t = 0; t < 8; ++t) {
    if (t < 7) stage(cur ^ 1, t + 1);
    for (int kc = 0; kc < 2; ++kc) {
      bf16x8 af[4], bfr[4];
      for (int mf=0; mf<4; ++mf) af[mf]  = frag_ld(&As[cur][0], wm + mf*16 + (lane&15), (lane>>4) + kc*4);
      for (int nf=0; nf<4; ++nf) bfr[nf] = frag_ld(&Bs[cur][0], wn + nf*16 + (lane&15), (lane>>4) + kc*4);
      for (int mf=0; mf<4; ++mf)
        for (int nf=0; nf<4; ++nf)
          acc[mf][nf] = __builtin_amdgcn_mfma_f32_16x16x32_bf16(af[mf], bfr[nf], acc[mf][nf], 0,0,0);
    }
    if (t < 7) {
      asm volatile("s_waitcnt vmcnt(0)" ::: "memory");
      __syncthreads();
      cur ^= 1;
    }
  }
  for (int mf=0; mf<4; ++mf)
    for (int nf=0; nf<4; ++nf) {
      int col = n0 + wn + nf*16 + (lane & 15);
      for (int r=0; r<4; ++r) {
        int row = m0 + wm + mf*16 + (lane>>4)*4 + r;
        ((unsigned short*)Cout)[(size_t)row*WIDTH + col] = f2bf(acc[mf][nf][r]);
      }
    }
}

// ---------------- output GEMM: x[8192][512] = ctx @ Wo^T, fp32 nt out ----------------
__global__ __launch_bounds__(256) void gemm_out(const bf16* __restrict__ A,
                                                const bf16* __restrict__ Bw,
                                                float* __restrict__ Cout) {
  __shared__ short As[2][128*64];
  __shared__ short Bs[2][64*64];

  const int bid = blockIdx.x;                // 512 blocks
  const int xcd = bid & 7;
  const int idx = bid >> 3;                  // 0..63
  const int m   = xcd*8 + (idx >> 3);        // 0..63
  const int y   = idx & 7;                   // 0..7 (64-col panels)

  const int lane = threadIdx.x & 63;
  const int wid  = threadIdx.x >> 6;
  const int m0 = m * 128;
  const int n0 = y * 64;
  const int wm = (wid >> 1) * 64;
  const int wn = (wid & 1) * 32;
  const int lrow = lane >> 3;
  const int swz  = ((lane & 7) ^ lrow) * 8;

  const f32x4 zero4 = {0.f,0.f,0.f,0.f};
  f32x4 acc[4][2];
  for (int i=0;i<4;++i) for (int j=0;j<2;++j) acc[i][j] = zero4;

  auto stage = [&](int buf, int t) {
    const int k0 = t * 64;
    for (int i = 0; i < 4; ++i) {
      int c = wid*4 + i;
      int row = c*8 + lrow;
      gload_lds16(A + (size_t)(m0 + row)*WIDTH + k0 + swz, &As[buf][c*512]);
    }
    for (int i = 0; i < 2; ++i) {
      int c = wid*2 + i;
      int row = c*8 + lrow;
      gload_lds16(Bw + (size_t)(n0 + row)*WIDTH + k0 + swz, &Bs[buf][c*512]);
    }
  };

  stage(0, 0);
  asm volatile("s_waitcnt vmcnt(0)" ::: "memory");
  __syncthreads();
  int cur = 0;

  for (int t = 0; t < 8; ++t) {
    if (t < 7) stage(cur ^ 1, t + 1);
    for (int kc = 0; kc < 2; ++kc) {
      bf16x8 af[4], bfr[2];
      for (int mf=0; mf<4; ++mf) af[mf]  = frag_ld(&As[cur][0], wm + mf*16 + (lane&15), (lane>>4) + kc*4);
      for (int nf=0; nf<2; ++nf) bfr[nf] = frag_ld(&Bs[cur][0], wn + nf*16 + (lane&15), (lane>>4) + kc*4);
      for (int mf=0; mf<4; ++mf)
        for (int nf=0; nf<2; ++nf)
          acc[mf][nf] = __builtin_amdgcn_mfma_f32_16x16x32_bf16(af[mf], bfr[nf], acc[mf][nf], 0,0,0);
    }
    if (t < 7) {
      asm volatile("s_waitcnt vmcnt(0)" ::: "memory");
      __syncthreads();
      cur ^= 1;
    }
  }
  for (int mf=0; mf<4; ++mf)
    for (int nf=0; nf<2; ++nf) {
      int col = n0 + wn + nf*16 + (lane & 15);
      for (int r=0; r<4; ++r) {
        int row = m0 + wm + mf*16 + (lane>>4)*4 + r;
        __builtin_nontemporal_store(acc[mf][nf][r], Cout + (size_t)row*WIDTH + col);
      }
    }
}

// ---------------- V transpose: per head (1024,64) -> (64,1024) ----------------
__global__ __launch_bounds__(256) void transpose_v(const bf16* __restrict__ Vh,
                                                   bf16* __restrict__ Vt) {
  __shared__ short t[64][72];
  int h  = blockIdx.x >> 4;
  int j0 = (blockIdx.x & 15) * 64;
  const bf16* src = Vh + (size_t)h * (SEQ*HD);
  bf16* dst = Vt + (size_t)h * (SEQ*HD);
  int tid = threadIdx.x;
  int r  = tid >> 2;
  int c0 = (tid & 3) * 16;
  bf16x8 v0 = *(const bf16x8*)(src + (size_t)(j0 + r)*HD + c0);
  bf16x8 v1 = *(const bf16x8*)(src + (size_t)(j0 + r)*HD + c0 + 8);
  for (int i = 0; i < 8; ++i) { t[r][c0+i] = v0[i]; t[r][c0+8+i] = v1[i]; }
  __syncthreads();
  bf16x8 w0, w1;
  for (int i = 0; i < 8; ++i) { w0[i] = t[c0+i][r]; w1[i] = t[c0+8+i][r]; }
  *(bf16x8*)(dst + (size_t)r*SEQ + j0 + c0)     = w0;
  *(bf16x8*)(dst + (size_t)r*SEQ + j0 + c0 + 8) = w1;
}

// ---------------- fused attention (2-pass, 8-wave, KVBLK=128) ----------------
// Block = 8 waves x 16 rows = 128 q-rows of one head; XCD-chunked (8 heads/XCD).
// Each jt covers 128 K/V columns as two 64-col sub-rounds sharing Ws; 8
// barriers per pass (was 16). Exact counted vmcnt(8) at the barrier.
__global__ __launch_bounds__(512) void attn_kernel(const bf16* __restrict__ Qh,
                                                   const bf16* __restrict__ Kh,
                                                   const bf16* __restrict__ Vt,
                                                   float* __restrict__ attn_out,
                                                   bf16* __restrict__ ctx) {
  __shared__ short Ks[2][128*64];    // [j 0..127][d 0..63], 2 sub-tiles of [64][64]
  __shared__ short Vs[2][128*64];    // 2 sub-tiles [d 0..63][j half*64..+63]
  __shared__ short Ws[8][16*64];

  const int lane = threadIdx.x & 63;
  const int wid  = threadIdx.x >> 6;         // 0..7
  const int bid  = blockIdx.x;
  const int xcd  = bid & 7;
  const int idx  = bid >> 3;                 // 0..63
  const int h    = xcd*8 + (idx >> 3);       // 8 heads/XCD
  const int i0   = (idx & 7) * 128;
  const int b  = h >> 3;
  const int nh = h & 7;

  const bf16* Qhead  = Qh + (size_t)h * (SEQ*HD);
  const bf16* Khead  = Kh + (size_t)h * (SEQ*HD);
  const bf16* Vthead = Vt + (size_t)h * (SEQ*HD);

  const int lrow = lane >> 3;
  const int swz  = ((lane & 7) ^ lrow) * 8;

  const int qrow = i0 + wid*16 + (lane & 15);
  bf16x8 qf[2];
  qf[0] = *(const bf16x8*)(Qhead + (size_t)qrow*HD + (lane>>4)*8);
  qf[1] = *(const bf16x8*)(Qhead + (size_t)qrow*HD + 32 + (lane>>4)*8);

  const f32x4 zero4 = {0.f,0.f,0.f,0.f};

  auto stageK = [&](int buf, int jt) {       // 2 chunks/wave: 128 j-rows
    const int j0 = jt * 128;
    for (int i = 0; i < 2; ++i) {
      int c = wid*2 + i;                     // 0..15
      gload_lds16(Khead + (size_t)(j0 + c*8 + lrow)*HD + swz, &Ks[buf][c*512]);
    }
  };
  auto stageV = [&](int buf, int jt) {       // 2 chunks/wave: 2 sub-tiles x 64 d-rows
    const int j0 = jt * 128;
    for (int i = 0; i < 2; ++i) {
      int c = wid*2 + i;                     // 0..15
      int sub = c >> 3, dr = (c & 7)*8 + lrow;
      gload_lds16(Vthead + (size_t)dr*SEQ + j0 + sub*64 + swz, &Vs[buf][c*512]);
    }
  };

  // ---- pass A: denominators ----
  float lsum[4] = {0.f,0.f,0.f,0.f};
  stageK(0, 0);
  asm volatile("s_waitcnt vmcnt(0)" ::: "memory");
  __syncthreads();
  int cur = 0;
  for (int jt = 0; jt < 8; ++jt) {
    if (jt < 7) stageK(cur ^ 1, jt + 1);
    #pragma unroll
    for (int half = 0; half < 2; ++half) {
      const short* Kt = &Ks[cur][half*4096];
      f32x4 sac[4] = {zero4, zero4, zero4, zero4};
      __builtin_amdgcn_s_setprio(1);
      for (int kc = 0; kc < 2; ++kc)
        for (int jf = 0; jf < 4; ++jf) {
          bf16x8 kf = frag_ld(Kt, jf*16 + (lane & 15), (lane>>4) + kc*4);
          sac[jf] = __builtin_amdgcn_mfma_f32_16x16x32_bf16(qf[kc], kf, sac[jf], 0, 0, 0);
        }
      __builtin_amdgcn_s_setprio(0);
      for (int jf = 0; jf < 4; ++jf)
        for (int r = 0; r < 4; ++r)
          lsum[r] += __expf(sac[jf][r] * SCALE_F);
    }
    if (jt < 7) {
      asm volatile("s_waitcnt vmcnt(0)" ::: "memory");
      __syncthreads();
      cur ^= 1;
    }
  }
  for (int m = 1; m < 16; m <<= 1)
    for (int r = 0; r < 4; ++r)
      lsum[r] += __shfl_xor(lsum[r], m, 64);
  float linv[4];
  for (int r = 0; r < 4; ++r) linv[r] = 1.0f / lsum[r];
  __syncthreads();

  // ---- pass B ----
  f32x4 cacc[4] = {zero4, zero4, zero4, zero4};
  short* Wsw = &Ws[wid][0];
  float* awbase = attn_out + (size_t)((size_t)h*SEQ + i0 + wid*16)*SEQ;
  stageK(0, 0); stageV(0, 0);
  asm volatile("s_waitcnt vmcnt(0)" ::: "memory");
  __syncthreads();
  cur = 0;
  for (int jt = 0; jt < 8; ++jt) {
    if (jt < 7) { stageK(cur ^ 1, jt + 1); stageV(cur ^ 1, jt + 1); }  // 4 loads, oldest
    const int j0 = jt * 128;
    #pragma unroll
    for (int half = 0; half < 2; ++half) {
      const short* Kt  = &Ks[cur][half*4096];
      const short* Vtt = &Vs[cur][half*4096];
      f32x4 sac[4] = {zero4, zero4, zero4, zero4};
      __builtin_amdgcn_s_setprio(1);
      for (int kc = 0; kc < 2; ++kc)
        for (int jf = 0; jf < 4; ++jf) {
          bf16x8 kf = frag_ld(Kt, jf*16 + (lane & 15), (lane>>4) + kc*4);
          sac[jf] = __builtin_amdgcn_mfma_f32_16x16x32_bf16(qf[kc], kf, sac[jf], 0, 0, 0);
        }
      __builtin_amdgcn_s_setprio(0);
      // normalized bf16 P -> Ws (PV operand AND attn_out source)
      for (int jf = 0; jf < 4; ++jf)
        for (int r = 0; r < 4; ++r) {
          float w = __expf(sac[jf][r] * SCALE_F) * linv[r];
          int row = (lane>>4)*4 + r;
          int col = jf*16 + (lane & 15);
          Wsw[row*64 + (((col>>3) ^ (row & 7))<<3) + (col & 7)] = (short)f2bf(w);
        }
      asm volatile("s_waitcnt lgkmcnt(0)" ::: "memory");  // Ws visible; pins load<store order
      __builtin_amdgcn_s_setprio(1);
      for (int kc = 0; kc < 2; ++kc) {
        bf16x8 wa = frag_ld(Wsw, lane & 15, (lane>>4) + kc*4);
        for (int df = 0; df < 4; ++df) {
          bf16x8 vb = frag_ld(Vtt, df*16 + (lane & 15), (lane>>4) + kc*4);
          cacc[df] = __builtin_amdgcn_mfma_f32_16x16x32_bf16(wa, vb, cacc[df], 0, 0, 0);
        }
      }
      __builtin_amdgcn_s_setprio(0);
      // attn_out: 4x f32x4 non-temporal, 256B contiguous per 16-lane group
      #pragma unroll
      for (int s = 0; s < 4; ++s) {
        int row = (lane>>4) + s*4;
        int lu  = (lane & 15) >> 1;
        uint2 pv = *(const uint2*)(Wsw + row*64 + ((lu ^ (row & 7)) << 3) + (lane & 1)*4);
        f32x4 o;
        o[0] = bf2f((unsigned short)(pv.x & 0xffff));
        o[1] = bf2f((unsigned short)(pv.x >> 16));
        o[2] = bf2f((unsigned short)(pv.y & 0xffff));
        o[3] = bf2f((unsigned short)(pv.y >> 16));
        __builtin_nontemporal_store(o,
            (f32x4*)(awbase + (size_t)row*SEQ + j0 + half*64 + (lane & 15)*4));
      }
    }
    if (jt < 7) {
      // exact: this jt's 8 stores follow the 4 staged loads -> vmcnt(8)
      // guarantees next tile's loads retired; stores stay in flight.
      asm volatile("s_waitcnt vmcnt(8) lgkmcnt(0)" ::: "memory");
      __builtin_amdgcn_s_barrier();
      cur ^= 1;
    }
  }
  for (int df = 0; df < 4; ++df)
    for (int r = 0; r < 4; ++r) {
      int irow = i0 + wid*16 + (lane>>4)*4 + r;
      ((unsigned short*)ctx)[(size_t)(b*SEQ + irow)*WIDTH + nh*HD + df*16 + (lane & 15)]
          = f2bf(cacc[df][r]);
    }
}

// ---------------- launcher ----------------
extern "C" void kernel_launch(void* const* d_in, const int* in_sizes, int n_in,
                              void* d_out, int out_size, void* d_ws, size_t ws_size,
                              hipStream_t stream) {
  const float* q  = (const float*)d_in[0];
  const float* k  = (const float*)d_in[1];
  const float* v  = (const float*)d_in[2];
  const float* wq = (const float*)d_in[3];
  const float* wk = (const float*)d_in[4];
  const float* wv = (const float*)d_in[5];
  const float* wo = (const float*)d_in[6];

  bf16* wsb = (bf16*)d_ws;
  bf16* qb  = wsb;
  bf16* kb  = qb + 4194304;
  bf16* vb  = kb + 4194304;
  bf16* wqb = vb + 4194304;
  bf16* wkb = wqb + 262144;
  bf16* wvb = wkb + 262144;
  bf16* wob = wvb + 262144;
  bf16* Qh  = wob + 262144;
  bf16* Kh  = Qh + 4194304;
  bf16* Vh  = Kh + 4194304;
  bf16* Vt  = Vh + 4194304;
  bf16* ctx = Vt + 4194304;

  float* x_out    = (float*)d_out;             // (8,1024,512)
  float* attn_out = (float*)d_out + 4194304;   // (8,8,1024,1024)

  cast_all_kernel<<<13312, 256, 0, stream>>>(q, k, v, wq, wk, wv, wo, wsb);
  gemm_qkv<<<768, 256, 0, stream>>>(qb, kb, vb, wqb, wkb, wvb, Qh, Kh, Vh);
  transpose_v<<<1024, 256, 0, stream>>>(Vh, Vt);
  attn_kernel<<<512, 512, 0, stream>>>(Qh, Kh, Vt, attn_out, ctx);
  gemm_out<<<512, 256, 0, stream>>>(ctx, wob, x_out);
}